// Round 12
// baseline (583.769 us; speedup 1.0000x reference)
//
#include <hip/hip_runtime.h>
#include <stdint.h>

typedef __attribute__((ext_vector_type(4)))  float    f32x4;
typedef __attribute__((ext_vector_type(16))) float    f32x16;
typedef __attribute__((ext_vector_type(8)))  short    s16x8;
typedef __attribute__((ext_vector_type(4)))  short    s16x4;
typedef __attribute__((ext_vector_type(8)))  _Float16 f16x8;

#define DEV __device__ __forceinline__

// sign of e_a * e_b in Cl(4,1), METRIC=(1,1,1,1,-1): C[a,b,a^b]
DEV float blade_sign(int a, int b){
    int s = 0, t = a >> 1;
    while (t){ s += __popc(t & b); t >>= 1; }
    float sg = (s & 1) ? -1.0f : 1.0f;
    return ((a & b) & 16) ? -sg : sg;
}
DEV short f2h(float v){
    _Float16 h = (_Float16)v;                 // RNE f32->f16
    return __builtin_bit_cast(short, h);
}
DEV float h2f(short b){
    return (float)__builtin_bit_cast(_Float16, b);
}
DEV void wait_vm(int n){                      // literal-arg folded vmcnt
    if (n == 8)      asm volatile("s_waitcnt vmcnt(8)" ::: "memory");
    else if (n == 6) asm volatile("s_waitcnt vmcnt(6)" ::: "memory");
    else if (n == 4) asm volatile("s_waitcnt vmcnt(4)" ::: "memory");
    else             asm volatile("s_waitcnt vmcnt(0)" ::: "memory");
}

// ---------------- cast x (f32) -> f16, 8 elems/thread ----------------
__global__ __launch_bounds__(256) void cast_f32_f16(const float* __restrict__ in,
                                                    short* __restrict__ out){
    const size_t idx = (size_t)blockIdx.x * 256 + threadIdx.x;
    const float4* p = reinterpret_cast<const float4*>(in) + idx * 2;
    float4 a = p[0], b = p[1];
    s16x8 o;
    o[0]=f2h(a.x); o[1]=f2h(a.y); o[2]=f2h(a.z); o[3]=f2h(a.w);
    o[4]=f2h(b.x); o[5]=f2h(b.y); o[6]=f2h(b.z); o[7]=f2h(b.w);
    *reinterpret_cast<s16x8*>(out + idx * 8) = o;
}

// ------- build WmatT f16: WmT[o*32+kb][i*32+l] = W[o,i,kb^l]*C[kb^l,l,kb] -------
DEV void build_wmat_body(const float* __restrict__ W, short* __restrict__ WmT,
                         int idx){
    const int n  = idx >> 9;
    const int kg = idx & 511;
    const int o = n >> 5, kb = n & 31;
    const int i = kg >> 2, l0 = (kg & 3) * 8;
    const float* wrow = W + (size_t)(o * 128 + i) * 32;
    s16x8 v;
    #pragma unroll
    for (int e = 0; e < 8; ++e){
        const int l = l0 + e, j = kb ^ l;
        v[e] = f2h(wrow[j] * blade_sign(j, l));
    }
    *reinterpret_cast<s16x8*>(WmT + (size_t)n * 4096 + kg * 8) = v;
}

__global__ __launch_bounds__(256) void build_wmat(const float* __restrict__ W,
                                                  short* __restrict__ WmT){
    build_wmat_body(W, WmT, blockIdx.x * 256 + threadIdx.x);
}

__global__ __launch_bounds__(256) void build_wmat3(const float* __restrict__ Wq,
                                                   const float* __restrict__ Wk,
                                                   const float* __restrict__ Wv,
                                                   short* __restrict__ WmT3){
    const int w = blockIdx.y;
    const float* W = (w == 0) ? Wq : ((w == 1) ? Wk : Wv);
    build_wmat_body(W, WmT3 + (size_t)w * 4096 * 4096,
                    blockIdx.x * 256 + threadIdx.x);
}

// ---------------- per-(b,h,s) norms over 512 features (q and k) ----------------
__global__ __launch_bounds__(256) void row_norms(const short* __restrict__ Q,
                                                 const short* __restrict__ Kq,
                                                 float* __restrict__ Nq,
                                                 float* __restrict__ Nk){
    const int row  = blockIdx.x * 4 + (threadIdx.x >> 6);
    const int lane = threadIdx.x & 63;
    const int b = row >> 13, h = (row >> 10) & 7, s = row & 1023;
    const size_t off = ((size_t)(b * 1024 + s)) * 4096 + h * 512 + lane * 8;
    s16x8 a = *reinterpret_cast<const s16x8*>(Q + off);
    s16x8 c = *reinterpret_cast<const s16x8*>(Kq + off);
    float sq = 0.f, sk = 0.f;
    #pragma unroll
    for (int e = 0; e < 8; ++e){
        float fa = h2f(a[e]); sq = fmaf(fa, fa, sq);
        float fc = h2f(c[e]); sk = fmaf(fc, fc, sk);
    }
    #pragma unroll
    for (int m = 1; m < 64; m <<= 1){
        sq += __shfl_xor(sq, m);
        sk += __shfl_xor(sk, m);
    }
    if (lane == 0){ Nq[row] = sq; Nk[row] = sk; }
}

// -------- softmax per row, in place: read 1024 f32, write 1024 f16 at row head --------
__global__ __launch_bounds__(256) void softmax_rows(float* __restrict__ Sc){
    const int row  = blockIdx.x * 4 + (threadIdx.x >> 6);
    const int lane = threadIdx.x & 63;
    float* p = Sc + (size_t)row * 1024;
    float v[16];
    float mx = -3.0e38f;
    #pragma unroll
    for (int j = 0; j < 16; ++j){ v[j] = p[lane + j * 64]; mx = fmaxf(mx, v[j]); }
    #pragma unroll
    for (int m = 1; m < 64; m <<= 1) mx = fmaxf(mx, __shfl_xor(mx, m));
    float sum = 0.f;
    #pragma unroll
    for (int j = 0; j < 16; ++j){ v[j] = __expf(v[j] - mx); sum += v[j]; }
    #pragma unroll
    for (int m = 1; m < 64; m <<= 1) sum += __shfl_xor(sum, m);
    const float inv = 1.0f / sum;
    short* pb = reinterpret_cast<short*>(p);
    #pragma unroll
    for (int j = 0; j < 16; ++j) pb[lane + j * 64] = f2h(v[j] * inv);
}

#define GLOAD_LDS(gp, lp) \
    __builtin_amdgcn_global_load_lds( \
        (const __attribute__((address_space(1))) void*)(const void*)(gp), \
        (__attribute__((address_space(3))) void*)(void*)(lp), 16, 0, 0)

// =======================================================================
// QKV GEMM (qkv5): qkv4's proven structure (256x128 tile, BK=32, 4 waves,
// ring-2 48KB -> 3 blocks/CU, 768-block clean round, counted vmcnt(6),
// two barriers/tile, chunk-XOR swizzle) but with 32x32x16 MFMA:
//  - 16 MFMA/tile/wave instead of 32 (half issue pressure, +11% rate)
//  - LDS image and staging IDENTICAL to qkv4 (HW-verified 0 conflicts)
//  - frag read: row = base + (lane&31), k-half = lane>>5; slot-XOR
//    (row>>1)&3 == ((lane&31)>>1)&3 (lane-only, same swizzle algebra)
//  - C/D: col = lane&31, row = (r&3)+8*(r>>2)+4*(lane>>5)  [m74/m101]
// Epilogue: blade l = lane&31 -> SIG is one per-lane scalar; normalize is
// a 5-hop shfl_xor per reg; V^T stores s16x4 over 4 consecutive t.
// =======================================================================
#define QKV_STAGE(BUF, T)                                                       \
  {                                                                             \
    const int sb = (BUF) * 12288;                                               \
    GLOAD_LDS(gA0 + (size_t)(T) * 32, lds + sb + dA + 0 * 512);                 \
    GLOAD_LDS(gA1 + (size_t)(T) * 32, lds + sb + dA + 1 * 512);                 \
    GLOAD_LDS(gA2 + (size_t)(T) * 32, lds + sb + dA + 2 * 512);                 \
    GLOAD_LDS(gA3 + (size_t)(T) * 32, lds + sb + dA + 3 * 512);                 \
    GLOAD_LDS(gB0 + (size_t)(T) * 32, lds + sb + dB + 0 * 512);                 \
    GLOAD_LDS(gB1 + (size_t)(T) * 32, lds + sb + dB + 1 * 512);                 \
  }

__global__ __launch_bounds__(256, 3) void versor_gemm_qkv5(
    const short* __restrict__ Xf,       // A: 2048 x 4096
    const short* __restrict__ WmT3,     // B: 12288 x 4096 (q,k,v stacked)
    short* __restrict__ OQ,
    short* __restrict__ OK,
    short* __restrict__ OV)
{
    __shared__ short lds[2 * 12288];    // 2 bufs x (A 8192 | B 4096) shorts

    const int tid  = threadIdx.x;
    const int lane = tid & 63;
    const int wid  = tid >> 6;          // 0..3
    const int wm   = wid >> 1;          // 0..1  (128-row half)
    const int wn   = wid & 1;           // 0..1  (64-col half)
    const int rl   = lane & 31;
    const int xh   = lane >> 5;

    // XCD ownership swizzle: grid (96, 8); xcd owns 12 col-panels, row-fast
    const int wg  = blockIdx.x + blockIdx.y * 96;
    const int xcd = wg & 7;
    const int u   = wg >> 3;            // 0..95
    const int bm  = u & 7;
    const int bn  = xcd * 12 + (u >> 3);
    const int row0 = bm * 256;
    const int col0 = bn * 128;
    const int lda = 4096, ldb = 4096;

    // staging (identical to qkv4): A 256x32 = 16 chunks (4/wave), B 8 (2/wave)
    const int jsw = ((lane & 3) ^ ((lane >> 3) & 3)) * 8;
    const short* gA0 = Xf + (size_t)(row0 + wid * 64 + (lane >> 2)) * lda + jsw;
    const short* gA1 = gA0 + (size_t)16 * lda;
    const short* gA2 = gA0 + (size_t)32 * lda;
    const short* gA3 = gA0 + (size_t)48 * lda;
    const short* gB0 = WmT3 + (size_t)(col0 + wid * 32 + (lane >> 2)) * ldb + jsw;
    const short* gB1 = gB0 + (size_t)16 * ldb;
    const int dA = wid * 4 * 512;            // A chunks at [0, 8192)
    const int dB = 8192 + wid * 2 * 512;     // B chunks at [8192, 12288)

    // 32x32x16 frag read bases: row = base + rl; k-half chunk = ks*2 + xh,
    // stored at slot ^ ((rl>>1)&3)
    const int sw  = (rl >> 1) & 3;
    const int ok0 = ((0 + xh) ^ sw) * 8;     // kstep 0
    const int ok1 = ((2 + xh) ^ sw) * 8;     // kstep 1
    const int arow = (wm * 128 + rl) * 32;          // + m*1024
    const int brow = 8192 + (wn * 64 + rl) * 32;    // + n*1024

    f32x16 acc[4][2];
    #pragma unroll
    for (int i = 0; i < 4; ++i)
        #pragma unroll
        for (int j = 0; j < 2; ++j)
            #pragma unroll
            for (int r = 0; r < 16; ++r)
                acc[i][j][r] = 0.f;

    const int NT = 4096 >> 5;   // 128

    // prologue: stage tiles 0,1 into bufs 0,1 (6 gloads each / wave)
    QKV_STAGE(0, 0)
    QKV_STAGE(1, 1)

    for (int t = 0; t < NT; ++t){
        if (t + 1 < NT) wait_vm(6);   // t+1's 6 loads may remain in flight
        else            wait_vm(0);
        __builtin_amdgcn_s_barrier();
        asm volatile("" ::: "memory");
        __builtin_amdgcn_sched_barrier(0);

        const int bb = (t & 1) * 12288;
        f16x8 a0[2][2], bv[2][2];
        #pragma unroll
        for (int m = 0; m < 2; ++m){
            a0[m][0] = *reinterpret_cast<const f16x8*>(lds + bb + arow + m * 1024 + ok0);
            a0[m][1] = *reinterpret_cast<const f16x8*>(lds + bb + arow + m * 1024 + ok1);
        }
        #pragma unroll
        for (int n = 0; n < 2; ++n){
            bv[n][0] = *reinterpret_cast<const f16x8*>(lds + bb + brow + n * 1024 + ok0);
            bv[n][1] = *reinterpret_cast<const f16x8*>(lds + bb + brow + n * 1024 + ok1);
        }
        __builtin_amdgcn_s_setprio(1);
        #pragma unroll
        for (int m = 0; m < 2; ++m)
            #pragma unroll
            for (int n = 0; n < 2; ++n)
                #pragma unroll
                for (int k = 0; k < 2; ++k)
                    acc[m][n] = __builtin_amdgcn_mfma_f32_32x32x16_f16(
                        a0[m][k], bv[n][k], acc[m][n], 0, 0, 0);
        __builtin_amdgcn_s_setprio(0);

        f16x8 a1[2][2];
        #pragma unroll
        for (int m = 0; m < 2; ++m){
            a1[m][0] = *reinterpret_cast<const f16x8*>(lds + bb + arow + (2 + m) * 1024 + ok0);
            a1[m][1] = *reinterpret_cast<const f16x8*>(lds + bb + arow + (2 + m) * 1024 + ok1);
        }
        __builtin_amdgcn_s_setprio(1);
        #pragma unroll
        for (int m = 0; m < 2; ++m)
            #pragma unroll
            for (int n = 0; n < 2; ++n)
                #pragma unroll
                for (int k = 0; k < 2; ++k)
                    acc[2 + m][n] = __builtin_amdgcn_mfma_f32_32x32x16_f16(
                        a1[m][k], bv[n][k], acc[2 + m][n], 0, 0, 0);
        __builtin_amdgcn_s_setprio(0);

        // all waves finished reading buf[t&1] -> safe to overwrite
        __builtin_amdgcn_s_barrier();
        asm volatile("" ::: "memory");
        __builtin_amdgcn_sched_barrier(0);
        if (t + 2 < NT)
            QKV_STAGE(t & 1, t + 2)
    }

    // ---------------- epilogue (32x32 C/D layout) ----------------
    // reg r of tile (m,n): row = row0 + wm*128 + m*32 + (r&3)+8*(r>>2)+4*xh
    //                      col = col0 + wn*64 + n*32 + rl  (blade l = rl)

    // normalize each blade group (32 cols = 32 lanes within a half) to unit RMS
    #pragma unroll
    for (int m = 0; m < 4; ++m)
        #pragma unroll
        for (int n = 0; n < 2; ++n)
            #pragma unroll
            for (int r = 0; r < 16; ++r){
                const float v = acc[m][n][r];
                float ss = v * v;
                ss += __shfl_xor(ss, 1);
                ss += __shfl_xor(ss, 2);
                ss += __shfl_xor(ss, 4);
                ss += __shfl_xor(ss, 8);
                ss += __shfl_xor(ss, 16);
                acc[m][n][r] = v / sqrtf(ss * 0.03125f + 1e-6f);
            }

    const int zsel  = col0 >> 12;          // 0:Q 1:K 2:V
    const int cbase = (col0 & 4095) + wn * 64;   // + n*32 + rl
    const int rbase = row0 + wm * 128 + 4 * xh;  // + m*32 + (r&3)+8*(r>>2)

    if (zsel == 0){
        const float sg = blade_sign(rl, rl);     // blade = rl for every col
        #pragma unroll
        for (int m = 0; m < 4; ++m)
            #pragma unroll
            for (int n = 0; n < 2; ++n){
                const int c = cbase + n * 32 + rl;
                #pragma unroll
                for (int r = 0; r < 16; ++r){
                    const int R = rbase + m * 32 + (r & 3) + 8 * (r >> 2);
                    OQ[(size_t)R * 4096 + c] = f2h(acc[m][n][r] * sg);
                }
            }
    } else if (zsel == 1){
        #pragma unroll
        for (int m = 0; m < 4; ++m)
            #pragma unroll
            for (int n = 0; n < 2; ++n){
                const int c = cbase + n * 32 + rl;
                #pragma unroll
                for (int r = 0; r < 16; ++r){
                    const int R = rbase + m * 32 + (r & 3) + 8 * (r >> 2);
                    OK[(size_t)R * 4096 + c] = f2h(acc[m][n][r]);
                }
            }
    } else {
        // V^T store: (b,h,f,t) with 4 consecutive t per reg-quad
        #pragma unroll
        for (int m = 0; m < 4; ++m)
            #pragma unroll
            for (int n = 0; n < 2; ++n){
                const int c = cbase + n * 32 + rl;
                const int h = c >> 9, f = c & 511;
                #pragma unroll
                for (int q = 0; q < 4; ++q){
                    const int R0 = rbase + m * 32 + 8 * q;
                    const int b = R0 >> 10, t0 = R0 & 1023;
                    s16x4 pv;
                    #pragma unroll
                    for (int j = 0; j < 4; ++j) pv[j] = f2h(acc[m][n][4 * q + j]);
                    *reinterpret_cast<s16x4*>(OV + ((size_t)((b * 8 + h) * 512 + f)) * 1024 + t0) = pv;
                }
            }
    }
}

// =======================================================================
// 128x128 ring-3 pipelined GEMM (proven R6-R10): BK=32, 4 waves, 48 KB LDS
// -> 3 blocks/CU. vmcnt(4) counted, peeled tail. XOR swizzle. setprio.
// EPI: 3 = final (norm, f32)    5 = PV (f16, batched over z)
// =======================================================================
#define R3_TILE(T, WN, PF)                                                      \
  {                                                                             \
    const int bb = cur * 8192;                                                  \
    wait_vm(WN);                                                                \
    __builtin_amdgcn_s_barrier();                                               \
    asm volatile("" ::: "memory");                                              \
    __builtin_amdgcn_sched_barrier(0);                                          \
    const int sb = stg * 8192;                                                  \
    if (PF){                                                                    \
        GLOAD_LDS(gA0 + (size_t)((T) + 2) * 32, lds + sb + dA0);                \
        GLOAD_LDS(gA1 + (size_t)((T) + 2) * 32, lds + sb + dA1);                \
    }                                                                           \
    f16x8 av[4], bv[4];                                                         \
    _Pragma("unroll")                                                           \
    for (int i = 0; i < 4; ++i)                                                 \
        av[i] = *reinterpret_cast<const f16x8*>(lds + bb + ard + i * 512);      \
    bv[0] = *reinterpret_cast<const f16x8*>(lds + bb + brd + 0 * 512);          \
    bv[1] = *reinterpret_cast<const f16x8*>(lds + bb + brd + 1 * 512);          \
    __builtin_amdgcn_s_setprio(1);                                              \
    _Pragma("unroll")                                                           \
    for (int mi = 0; mi < 4; ++mi)                                              \
        _Pragma("unroll")                                                       \
        for (int ni = 0; ni < 2; ++ni)                                          \
            acc[mi][ni] = __builtin_amdgcn_mfma_f32_16x16x32_f16(               \
                av[mi], bv[ni], acc[mi][ni], 0, 0, 0);                          \
    __builtin_amdgcn_s_setprio(0);                                              \
    if (PF){                                                                    \
        GLOAD_LDS(gB0 + (size_t)((T) + 2) * 32, lds + sb + dB0);                \
        GLOAD_LDS(gB1 + (size_t)((T) + 2) * 32, lds + sb + dB1);                \
    }                                                                           \
    bv[2] = *reinterpret_cast<const f16x8*>(lds + bb + brd + 2 * 512);          \
    bv[3] = *reinterpret_cast<const f16x8*>(lds + bb + brd + 3 * 512);          \
    __builtin_amdgcn_s_setprio(1);                                              \
    _Pragma("unroll")                                                           \
    for (int mi = 0; mi < 4; ++mi)                                              \
        _Pragma("unroll")                                                       \
        for (int ni = 2; ni < 4; ++ni)                                          \
            acc[mi][ni] = __builtin_amdgcn_mfma_f32_16x16x32_f16(               \
                av[mi], bv[ni], acc[mi][ni], 0, 0, 0);                          \
    __builtin_amdgcn_s_setprio(0);                                              \
    cur = (cur == 2) ? 0 : cur + 1;                                             \
    stg = (stg == 2) ? 0 : stg + 1;                                             \
  }

template<int EPI, int CPX>
__global__ __launch_bounds__(256, 3) void versor_gemm_r3(
    const short* __restrict__ Abase, int lda,
    const short* __restrict__ Bbase, int ldb,
    int K, void* __restrict__ OutP)
{
    __shared__ short lds[3 * 8192];

    const int tid  = threadIdx.x;
    const int lane = tid & 63;
    const int wid  = tid >> 6;
    const int wr   = wid >> 1;
    const int wc   = wid & 1;
    const int z    = blockIdx.z;

    int bn, bm;
    if constexpr (CPX > 0){
        const int wg  = blockIdx.x + blockIdx.y * gridDim.x;
        const int xcd = wg & 7;
        const int u   = wg >> 3;
        bm = u & 15;
        bn = xcd * CPX + (u >> 4);
    } else {
        bn = blockIdx.x; bm = blockIdx.y;
    }

    const short* A = Abase;
    const short* B = Bbase;
    if constexpr (EPI == 5){
        A += (size_t)z * 1024 * 2048;
        B += (size_t)z * 512 * 1024;
    }
    const int row0 = bm * 128;
    const int col0 = bn * 128;

    const int jsw = ((lane & 3) ^ ((lane >> 3) & 3)) * 8;
    const short* gA0 = A + (size_t)(row0 + wid * 16 + (lane >> 2)) * lda + jsw;
    const short* gA1 = gA0 + (size_t)64 * lda;
    const short* gB0 = B + (size_t)(col0 + wid * 16 + (lane >> 2)) * ldb + jsw;
    const short* gB1 = gB0 + (size_t)64 * ldb;
    const int dA0 = wid * 512,        dA1 = 2048 + wid * 512;
    const int dB0 = 4096 + wid * 512, dB1 = 6144 + wid * 512;

    const int swz = ((lane >> 4) ^ (((lane & 15) >> 1) & 3)) * 8;
    const int ard = (wr * 64 + (lane & 15)) * 32 + swz;
    const int brd = 4096 + (wc * 64 + (lane & 15)) * 32 + swz;

    f32x4 acc[4][4];
    #pragma unroll
    for (int i = 0; i < 4; ++i)
        #pragma unroll
        for (int j = 0; j < 4; ++j)
            acc[i][j] = (f32x4){0.f, 0.f, 0.f, 0.f};

    const int NT = K >> 5;

    #pragma unroll
    for (int pt = 0; pt < 2; ++pt){
        const int sb = pt * 8192;
        GLOAD_LDS(gA0 + pt * 32, lds + sb + dA0);
        GLOAD_LDS(gA1 + pt * 32, lds + sb + dA1);
        GLOAD_LDS(gB0 + pt * 32, lds + sb + dB0);
        GLOAD_LDS(gB1 + pt * 32, lds + sb + dB1);
    }

    int cur = 0, stg = 2;
    for (int t = 0; t < NT - 1; ++t)
        R3_TILE(t, 4, (t + 2 < NT))
    R3_TILE(NT - 1, 0, false)

    const int rb = row0 + wr * 64 + (lane >> 4) * 4;
    const int cb = col0 + wc * 64 + (lane & 15);

    if constexpr (EPI == 3){
        #pragma unroll
        for (int mi = 0; mi < 4; ++mi){
            #pragma unroll
            for (int g = 0; g < 2; ++g){
                f32x4 a0 = acc[mi][2 * g], a1 = acc[mi][2 * g + 1];
                f32x4 ss = a0 * a0 + a1 * a1;
                #pragma unroll
                for (int m = 1; m < 16; m <<= 1){
                    ss.x += __shfl_xor(ss.x, m);
                    ss.y += __shfl_xor(ss.y, m);
                    ss.z += __shfl_xor(ss.z, m);
                    ss.w += __shfl_xor(ss.w, m);
                }
                f32x4 inv;
                inv.x = 1.0f / sqrtf(ss.x * 0.03125f + 1e-6f);
                inv.y = 1.0f / sqrtf(ss.y * 0.03125f + 1e-6f);
                inv.z = 1.0f / sqrtf(ss.z * 0.03125f + 1e-6f);
                inv.w = 1.0f / sqrtf(ss.w * 0.03125f + 1e-6f);
                acc[mi][2 * g]     = a0 * inv;
                acc[mi][2 * g + 1] = a1 * inv;
            }
        }
        float* Of = (float*)OutP;
        #pragma unroll
        for (int mi = 0; mi < 4; ++mi)
            #pragma unroll
            for (int ni = 0; ni < 4; ++ni)
                #pragma unroll
                for (int j = 0; j < 4; ++j)
                    Of[(size_t)(rb + mi * 16 + j) * 4096 + (cb + ni * 16)] = acc[mi][ni][j];
    }
    if constexpr (EPI == 5){
        short* Ob = (short*)OutP;
        const int b = z >> 3, h = z & 7;
        #pragma unroll
        for (int mi = 0; mi < 4; ++mi)
            #pragma unroll
            for (int ni = 0; ni < 4; ++ni)
                #pragma unroll
                for (int j = 0; j < 4; ++j)
                    Ob[(size_t)(b * 1024 + rb + mi * 16 + j) * 4096 + h * 512 + (cb + ni * 16)]
                        = f2h(acc[mi][ni][j]);
    }
}

// =======================================================================
// Scores kernel (256x256, 8 waves, ring-4, dyn 128KB LDS) with torque
// epilogue. Peeled tail (vmcnt 8 -> 4 -> 0).
// =======================================================================
#define SC_TILE(T, WN, PF)                                                      \
  {                                                                             \
    const int bb = ((T) & 3) * 16384;                                           \
    wait_vm(WN);                                                                \
    __builtin_amdgcn_s_barrier();                                               \
    asm volatile("" ::: "memory");                                              \
    __builtin_amdgcn_sched_barrier(0);                                          \
    if (PF){                                                                    \
        const int nb = (((T) + 3) & 3) * 16384;                                 \
        GLOAD_LDS(gA0 + (size_t)((T) + 3) * 32, lds + nb + dA0);                \
        GLOAD_LDS(gA1 + (size_t)((T) + 3) * 32, lds + nb + dA1);                \
    }                                                                           \
    f16x8 av[4], bv[4];                                                         \
    _Pragma("unroll")                                                           \
    for (int i = 0; i < 4; ++i){                                                \
        av[i] = *reinterpret_cast<const f16x8*>(lds + bb + ard + i * 512);      \
        bv[i] = *reinterpret_cast<const f16x8*>(lds + bb + brd + i * 512);      \
    }                                                                           \
    __builtin_amdgcn_s_setprio(1);                                              \
    _Pragma("unroll")                                                           \
    for (int mi = 0; mi < 4; ++mi)                                              \
        _Pragma("unroll")                                                       \
        for (int ni = 0; ni < 4; ++ni)                                          \
            acc[mi][ni] = __builtin_amdgcn_mfma_f32_16x16x32_f16(               \
                av[mi], bv[ni], acc[mi][ni], 0, 0, 0);                          \
    __builtin_amdgcn_s_setprio(0);                                              \
    if (PF){                                                                    \
        const int nb = (((T) + 3) & 3) * 16384;                                 \
        GLOAD_LDS(gB0 + (size_t)((T) + 3) * 32, lds + nb + dB0);                \
        GLOAD_LDS(gB1 + (size_t)((T) + 3) * 32, lds + nb + dB1);                \
    }                                                                           \
    f16x8 aw[4];                                                                \
    _Pragma("unroll")                                                           \
    for (int i = 0; i < 4; ++i)                                                 \
        aw[i] = *reinterpret_cast<const f16x8*>(lds + bb + ard + (4 + i) * 512);\
    __builtin_amdgcn_s_setprio(1);                                              \
    _Pragma("unroll")                                                           \
    for (int mi = 0; mi < 4; ++mi)                                              \
        _Pragma("unroll")                                                       \
        for (int ni = 0; ni < 4; ++ni)                                          \
            acc[4 + mi][ni] = __builtin_amdgcn_mfma_f32_16x16x32_f16(           \
                aw[mi], bv[ni], acc[4 + mi][ni], 0, 0, 0);                      \
    __builtin_amdgcn_s_setprio(0);                                              \
  }

__global__ __launch_bounds__(512, 2) void versor_gemm_sc(
    const short* __restrict__ Qbase, const short* __restrict__ Kbase,
    int K, float* __restrict__ OutP,
    const float* __restrict__ NqP, const float* __restrict__ NkP,
    const float* __restrict__ LamP)
{
    extern __shared__ short lds[];

    const int tid  = threadIdx.x;
    const int lane = tid & 63;
    const int wid  = tid >> 6;
    const int wm   = wid >> 2;
    const int wn   = wid & 3;
    const int z    = blockIdx.z;

    const int b = z >> 3, h = z & 7;
    const size_t off = (size_t)b * 1024 * 4096 + (size_t)h * 512;
    const short* A = Qbase + off;
    const short* B = Kbase + off;
    const int lda = 4096, ldb = 4096;
    const int row0 = blockIdx.y * 256;
    const int col0 = blockIdx.x * 256;

    const int jsw = ((lane & 3) ^ ((lane >> 3) & 3)) * 8;
    const short* gA0 = A + (size_t)(row0 + wid * 32 + (lane >> 2)) * lda + jsw;
    const short* gA1 = gA0 + (size_t)16 * lda;
    const short* gB0 = B + (size_t)(col0 + wid * 32 + (lane >> 2)) * ldb + jsw;
    const short* gB1 = gB0 + (size_t)16 * ldb;
    const int dA0 = wid * 1024, dA1 = dA0 + 512;
    const int dB0 = 8192 + wid * 1024, dB1 = dB0 + 512;

    const int swz = ((lane >> 4) ^ (((lane & 15) >> 1) & 3)) * 8;
    const int ard = (wm * 128 + (lane & 15)) * 32 + swz;
    const int brd = 8192 + (wn * 64 + (lane & 15)) * 32 + swz;

    f32x4 acc[8][4];
    #pragma unroll
    for (int i = 0; i < 8; ++i)
        #pragma unroll
        for (int j = 0; j < 4; ++j)
            acc[i][j] = (f32x4){0.f, 0.f, 0.f, 0.f};

    const int NT = K >> 5;   // 16

    #pragma unroll
    for (int pt = 0; pt < 3; ++pt){
        const int bb = pt * 16384;
        GLOAD_LDS(gA0 + pt * 32, lds + bb + dA0);
        GLOAD_LDS(gA1 + pt * 32, lds + bb + dA1);
        GLOAD_LDS(gB0 + pt * 32, lds + bb + dB0);
        GLOAD_LDS(gB1 + pt * 32, lds + bb + dB1);
    }

    for (int t = 0; t < NT - 2; ++t)
        SC_TILE(t, 8, (t + 3 < NT))
    SC_TILE(NT - 2, 4, false)
    SC_TILE(NT - 1, 0, false)

    const int rb = row0 + wm * 128 + (lane >> 4) * 4;
    const int cb = col0 + wn * 64 + (lane & 15);

    float* Of = OutP + (size_t)z * 1024 * 1024;
    const float lam = *LamP;
    const float* nq = NqP + z * 1024;
    const float* nk = NkP + z * 1024;
    #pragma unroll
    for (int mi = 0; mi < 8; ++mi)
        #pragma unroll
        for (int j = 0; j < 4; ++j){
            const int r = rb + mi * 16 + j;
            const float qn = nq[r];
            #pragma unroll
            for (int ni = 0; ni < 4; ++ni){
                const int c = cb + ni * 16;
                const float sc = acc[mi][ni][j];
                const float tq = sqrtf(fmaxf(qn * nk[c] - sc * sc, 0.0f) + 1e-6f);
                Of[(size_t)r * 1024 + c] = 0.25f * (sc + lam * tq);
            }
        }
}

// =======================================================================
extern "C" void kernel_launch(void* const* d_in, const int* in_sizes, int n_in,
                              void* d_out, int out_size, void* d_ws, size_t ws_size,
                              hipStream_t stream)
{
    (void)in_sizes; (void)n_in; (void)out_size; (void)ws_size;
    const float* x   = (const float*)d_in[0];
    const float* Wq  = (const float*)d_in[1];
    const float* Wk  = (const float*)d_in[2];
    const float* Wv  = (const float*)d_in[3];
    const float* Wo  = (const float*)d_in[4];
    const float* lam = (const float*)d_in[5];
    float* out = (float*)d_out;
    char*  ws  = (char*)d_ws;

    // workspace layout (~160.2 MB peak)
    short* Xf   = (short*)(ws);                             // 16 MB; later attn-out
    short* WmT3 = (short*)(ws + (16u  << 20));              // 96 MB (q,k,v); dead after QKV
    short* Qf   = (short*)(ws + (112u << 20));              // 16 MB
    short* Kf   = (short*)(ws + (128u << 20));              // 16 MB
    short* Vt   = (short*)(ws + (144u << 20));              // 16 MB (B,H,512,1024) f16
    float* Nq   = (float*)(ws + (160u << 20));              // 64 KB
    float* Nk   = (float*)(ws + (160u << 20) + (64u << 10));// 64 KB
    float* Sc   = (float*)(ws + (16u  << 20));              // 64 MB, overlays WmT3[0:64MB]
    short* WmTo = (short*)(ws + (80u  << 20));              // 32 MB, overlays WmT3[64:96MB]
    short* Attn = Xf;                                       // 16 MB, overlays Xf

    const int SC_LDS = 131072;
    hipFuncSetAttribute(reinterpret_cast<const void*>(versor_gemm_sc),
                        hipFuncAttributeMaxDynamicSharedMemorySize, SC_LDS);

    dim3 blk(256), blk8(512);
    cast_f32_f16<<<4096, blk, 0, stream>>>(x, Xf);

    dim3 gw3(8192, 3);
    build_wmat3<<<gw3, blk, 0, stream>>>(Wq, Wk, Wv, WmT3);

    // fused QKV v5: qkv4 structure + 32x32x16 MFMA; grid (96, 8) = 768 blocks
    dim3 gqkv(96, 8, 1);
    versor_gemm_qkv5<<<gqkv, blk, 0, stream>>>(Xf, WmT3, Qf, Kf, Vt);

    row_norms<<<4096, blk, 0, stream>>>(Qf, Kf, Nq, Nk);

    build_wmat<<<8192, blk, 0, stream>>>(Wo, WmTo);

    dim3 gsc(4, 4, 16);      // 256 blocks, 1/CU
    versor_gemm_sc<<<gsc, blk8, SC_LDS, stream>>>(Qf, Kf, 512, Sc, Nq, Nk, lam);
    softmax_rows<<<4096, blk, 0, stream>>>(Sc);

    dim3 gpv(4, 8, 16);      // 512 blocks
    versor_gemm_r3<5, 0><<<gpv, blk, 0, stream>>>(
        (const short*)Sc, 2048, Vt, 1024, 1024, Attn);

    dim3 gfin(32, 16, 1);    // 512 blocks, XCD swizzle CPX=4
    versor_gemm_r3<3, 4><<<gfin, blk, 0, stream>>>(
        Attn, 4096, WmTo, 4096, 4096, out);
}

// Round 13
// 526.011 us; speedup vs baseline: 1.1098x; 1.1098x over previous
//
#include <hip/hip_runtime.h>
#include <stdint.h>

typedef __attribute__((ext_vector_type(4))) float    f32x4;
typedef __attribute__((ext_vector_type(8))) short    s16x8;
typedef __attribute__((ext_vector_type(4))) short    s16x4;
typedef __attribute__((ext_vector_type(8))) _Float16 f16x8;

#define DEV __device__ __forceinline__

// sign of e_a * e_b in Cl(4,1), METRIC=(1,1,1,1,-1): C[a,b,a^b]
DEV float blade_sign(int a, int b){
    int s = 0, t = a >> 1;
    while (t){ s += __popc(t & b); t >>= 1; }
    float sg = (s & 1) ? -1.0f : 1.0f;
    return ((a & b) & 16) ? -sg : sg;
}
DEV short f2h(float v){
    _Float16 h = (_Float16)v;                 // RNE f32->f16
    return __builtin_bit_cast(short, h);
}
DEV float h2f(short b){
    return (float)__builtin_bit_cast(_Float16, b);
}
DEV void wait_vm(int n){                      // literal-arg folded vmcnt
    if (n == 8)      asm volatile("s_waitcnt vmcnt(8)" ::: "memory");
    else if (n == 6) asm volatile("s_waitcnt vmcnt(6)" ::: "memory");
    else if (n == 4) asm volatile("s_waitcnt vmcnt(4)" ::: "memory");
    else             asm volatile("s_waitcnt vmcnt(0)" ::: "memory");
}

// ---------------- cast x (f32) -> f16, 8 elems/thread ----------------
__global__ __launch_bounds__(256) void cast_f32_f16(const float* __restrict__ in,
                                                    short* __restrict__ out){
    const size_t idx = (size_t)blockIdx.x * 256 + threadIdx.x;
    const float4* p = reinterpret_cast<const float4*>(in) + idx * 2;
    float4 a = p[0], b = p[1];
    s16x8 o;
    o[0]=f2h(a.x); o[1]=f2h(a.y); o[2]=f2h(a.z); o[3]=f2h(a.w);
    o[4]=f2h(b.x); o[5]=f2h(b.y); o[6]=f2h(b.z); o[7]=f2h(b.w);
    *reinterpret_cast<s16x8*>(out + idx * 8) = o;
}

// ------- build WmatT f16: WmT[o*32+kb][i*32+l] = W[o,i,kb^l]*C[kb^l,l,kb] -------
DEV void build_wmat_body(const float* __restrict__ W, short* __restrict__ WmT,
                         int idx){
    const int n  = idx >> 9;
    const int kg = idx & 511;
    const int o = n >> 5, kb = n & 31;
    const int i = kg >> 2, l0 = (kg & 3) * 8;
    const float* wrow = W + (size_t)(o * 128 + i) * 32;
    s16x8 v;
    #pragma unroll
    for (int e = 0; e < 8; ++e){
        const int l = l0 + e, j = kb ^ l;
        v[e] = f2h(wrow[j] * blade_sign(j, l));
    }
    *reinterpret_cast<s16x8*>(WmT + (size_t)n * 4096 + kg * 8) = v;
}

__global__ __launch_bounds__(256) void build_wmat(const float* __restrict__ W,
                                                  short* __restrict__ WmT){
    build_wmat_body(W, WmT, blockIdx.x * 256 + threadIdx.x);
}

__global__ __launch_bounds__(256) void build_wmat3(const float* __restrict__ Wq,
                                                   const float* __restrict__ Wk,
                                                   const float* __restrict__ Wv,
                                                   short* __restrict__ WmT3){
    const int w = blockIdx.y;
    const float* W = (w == 0) ? Wq : ((w == 1) ? Wk : Wv);
    build_wmat_body(W, WmT3 + (size_t)w * 4096 * 4096,
                    blockIdx.x * 256 + threadIdx.x);
}

// ---------------- per-(b,h,s) norms over 512 features (q and k) ----------------
__global__ __launch_bounds__(256) void row_norms(const short* __restrict__ Q,
                                                 const short* __restrict__ Kq,
                                                 float* __restrict__ Nq,
                                                 float* __restrict__ Nk){
    const int row  = blockIdx.x * 4 + (threadIdx.x >> 6);
    const int lane = threadIdx.x & 63;
    const int b = row >> 13, h = (row >> 10) & 7, s = row & 1023;
    const size_t off = ((size_t)(b * 1024 + s)) * 4096 + h * 512 + lane * 8;
    s16x8 a = *reinterpret_cast<const s16x8*>(Q + off);
    s16x8 c = *reinterpret_cast<const s16x8*>(Kq + off);
    float sq = 0.f, sk = 0.f;
    #pragma unroll
    for (int e = 0; e < 8; ++e){
        float fa = h2f(a[e]); sq = fmaf(fa, fa, sq);
        float fc = h2f(c[e]); sk = fmaf(fc, fc, sk);
    }
    #pragma unroll
    for (int m = 1; m < 64; m <<= 1){
        sq += __shfl_xor(sq, m);
        sk += __shfl_xor(sk, m);
    }
    if (lane == 0){ Nq[row] = sq; Nk[row] = sk; }
}

// -------- softmax per row, in place: read 1024 f32, write 1024 f16 at row head --------
__global__ __launch_bounds__(256) void softmax_rows(float* __restrict__ Sc){
    const int row  = blockIdx.x * 4 + (threadIdx.x >> 6);
    const int lane = threadIdx.x & 63;
    float* p = Sc + (size_t)row * 1024;
    float v[16];
    float mx = -3.0e38f;
    #pragma unroll
    for (int j = 0; j < 16; ++j){ v[j] = p[lane + j * 64]; mx = fmaxf(mx, v[j]); }
    #pragma unroll
    for (int m = 1; m < 64; m <<= 1) mx = fmaxf(mx, __shfl_xor(mx, m));
    float sum = 0.f;
    #pragma unroll
    for (int j = 0; j < 16; ++j){ v[j] = __expf(v[j] - mx); sum += v[j]; }
    #pragma unroll
    for (int m = 1; m < 64; m <<= 1) sum += __shfl_xor(sum, m);
    const float inv = 1.0f / sum;
    short* pb = reinterpret_cast<short*>(p);
    #pragma unroll
    for (int j = 0; j < 16; ++j) pb[lane + j * 64] = f2h(v[j] * inv);
}

#define GLOAD_LDS(gp, lp) \
    __builtin_amdgcn_global_load_lds( \
        (const __attribute__((address_space(1))) void*)(const void*)(gp), \
        (__attribute__((address_space(3))) void*)(void*)(lp), 16, 0, 0)

// =======================================================================
// Wide GEMM (R8's proven qkv2 structure, templated epilogue):
// 256(M)x128(N) tile, BK=32, 4 waves (2x2, wave 128x64), ring-3 LDS
// (3 x 24KB = 72KB dyn) -> 2 blocks/CU. Counted vmcnt(6) (stage t+2
// during t), peeled last tile vmcnt(0). XOR chunk swizzle (0 conflicts,
// HW-verified R5-R10). setprio. XCD swizzle: xcd owns CPX col-panels,
// row-fast (8 row-blocks).
// EPI 0: fused QKV (col0>>12 -> Q*SIG / K / V^T), B = WmT3 stack.
// EPI 3: final projection (norm, f32 store to OutF).
// =======================================================================
#define W_TILE(T, WN, PF)                                                       \
  {                                                                             \
    const int bb = cur * 12288;                                                 \
    wait_vm(WN);                                                                \
    __builtin_amdgcn_s_barrier();                                               \
    asm volatile("" ::: "memory");                                              \
    __builtin_amdgcn_sched_barrier(0);                                          \
    const int sb = stg * 12288;                                                 \
    if (PF){                                                                    \
        GLOAD_LDS(gA0 + (size_t)((T) + 2) * 32, lds + sb + dA + 0 * 512);       \
        GLOAD_LDS(gA1 + (size_t)((T) + 2) * 32, lds + sb + dA + 1 * 512);       \
        GLOAD_LDS(gA2 + (size_t)((T) + 2) * 32, lds + sb + dA + 2 * 512);       \
        GLOAD_LDS(gA3 + (size_t)((T) + 2) * 32, lds + sb + dA + 3 * 512);       \
    }                                                                           \
    f16x8 av[4], bv[4];                                                         \
    _Pragma("unroll")                                                           \
    for (int i = 0; i < 4; ++i){                                                \
        av[i] = *reinterpret_cast<const f16x8*>(lds + bb + ard + i * 512);      \
        bv[i] = *reinterpret_cast<const f16x8*>(lds + bb + brd + i * 512);      \
    }                                                                           \
    __builtin_amdgcn_s_setprio(1);                                              \
    _Pragma("unroll")                                                           \
    for (int mi = 0; mi < 4; ++mi)                                              \
        _Pragma("unroll")                                                       \
        for (int ni = 0; ni < 4; ++ni)                                          \
            acc[mi][ni] = __builtin_amdgcn_mfma_f32_16x16x32_f16(               \
                av[mi], bv[ni], acc[mi][ni], 0, 0, 0);                          \
    __builtin_amdgcn_s_setprio(0);                                              \
    if (PF){                                                                    \
        GLOAD_LDS(gB0 + (size_t)((T) + 2) * 32, lds + sb + dB + 0 * 512);       \
        GLOAD_LDS(gB1 + (size_t)((T) + 2) * 32, lds + sb + dB + 1 * 512);       \
    }                                                                           \
    f16x8 aw[4];                                                                \
    _Pragma("unroll")                                                           \
    for (int i = 0; i < 4; ++i)                                                 \
        aw[i] = *reinterpret_cast<const f16x8*>(lds + bb + ard + (4 + i) * 512);\
    __builtin_amdgcn_s_setprio(1);                                              \
    _Pragma("unroll")                                                           \
    for (int mi = 0; mi < 4; ++mi)                                              \
        _Pragma("unroll")                                                       \
        for (int ni = 0; ni < 4; ++ni)                                          \
            acc[4 + mi][ni] = __builtin_amdgcn_mfma_f32_16x16x32_f16(           \
                aw[mi], bv[ni], acc[4 + mi][ni], 0, 0, 0);                      \
    __builtin_amdgcn_s_setprio(0);                                              \
    cur = (cur == 2) ? 0 : cur + 1;                                             \
    stg = (stg == 2) ? 0 : stg + 1;                                             \
  }

template<int EPI, int CPX>
__global__ __launch_bounds__(256, 2) void versor_gemm_wide(
    const short* __restrict__ Abase,    // 2048 x 4096
    const short* __restrict__ Bbase,    // (3x)4096 x 4096
    short* __restrict__ OQ,
    short* __restrict__ OK,
    short* __restrict__ OV,
    float* __restrict__ OutF)
{
    extern __shared__ short lds[];   // 3 bufs x (A 8192 | B 4096) shorts

    const int tid  = threadIdx.x;
    const int lane = tid & 63;
    const int wid  = tid >> 6;        // 0..3
    const int wm   = wid >> 1;        // 0..1  (128-row half)
    const int wn   = wid & 1;         // 0..1  (64-col half)

    // XCD ownership swizzle: xcd owns CPX col-panels, row-fast (8 rows)
    const int wg  = blockIdx.x + blockIdx.y * gridDim.x;
    const int xcd = wg & 7;
    const int u   = wg >> 3;
    const int bm  = u & 7;
    const int bn  = xcd * CPX + (u >> 3);
    const int row0 = bm * 256;
    const int col0 = bn * 128;

    const int lda = 4096, ldb = 4096;

    // staging: A 256x32 = 16 chunks (4/wave), B 128x32 = 8 chunks (2/wave)
    const int jsw = ((lane & 3) ^ ((lane >> 3) & 3)) * 8;
    const short* gA0 = Abase + (size_t)(row0 + wid * 64 + (lane >> 2)) * lda + jsw;
    const short* gA1 = gA0 + (size_t)16 * lda;
    const short* gA2 = gA0 + (size_t)32 * lda;
    const short* gA3 = gA0 + (size_t)48 * lda;
    const short* gB0 = Bbase + (size_t)(col0 + wid * 32 + (lane >> 2)) * ldb + jsw;
    const short* gB1 = gB0 + (size_t)16 * ldb;
    const int dA = wid * 4 * 512;            // A chunks at [0, 8192)
    const int dB = 8192 + wid * 2 * 512;     // B chunks at [8192, 12288)

    // ds_read frag bases (swizzled, lane-only XOR)
    const int swz = ((lane >> 4) ^ (((lane & 15) >> 1) & 3)) * 8;
    const int ard = (wm * 128 + (lane & 15)) * 32 + swz;          // + mi*512
    const int brd = 8192 + (wn * 64 + (lane & 15)) * 32 + swz;    // + ni*512

    f32x4 acc[8][4];
    #pragma unroll
    for (int i = 0; i < 8; ++i)
        #pragma unroll
        for (int j = 0; j < 4; ++j)
            acc[i][j] = (f32x4){0.f, 0.f, 0.f, 0.f};

    const int NT = 4096 >> 5;   // 128

    // prologue: stage tiles 0,1 into bufs 0,1 (6 gloads each / wave)
    #pragma unroll
    for (int pt = 0; pt < 2; ++pt){
        const int sb = pt * 12288;
        GLOAD_LDS(gA0 + pt * 32, lds + sb + dA + 0 * 512);
        GLOAD_LDS(gA1 + pt * 32, lds + sb + dA + 1 * 512);
        GLOAD_LDS(gA2 + pt * 32, lds + sb + dA + 2 * 512);
        GLOAD_LDS(gA3 + pt * 32, lds + sb + dA + 3 * 512);
        GLOAD_LDS(gB0 + pt * 32, lds + sb + dB + 0 * 512);
        GLOAD_LDS(gB1 + pt * 32, lds + sb + dB + 1 * 512);
    }

    int cur = 0, stg = 2;
    for (int t = 0; t < NT - 1; ++t)
        W_TILE(t, 6, (t + 2 < NT))
    W_TILE(NT - 1, 0, false)

    // ---------------- epilogue ----------------
    const int rb = row0 + wm * 128 + (lane >> 4) * 4;   // + mi*16 + j

    // normalize each 32-col blade group to unit RMS
    #pragma unroll
    for (int mi = 0; mi < 8; ++mi){
        #pragma unroll
        for (int g = 0; g < 2; ++g){
            f32x4 a0 = acc[mi][2 * g], a1 = acc[mi][2 * g + 1];
            f32x4 ss = a0 * a0 + a1 * a1;
            #pragma unroll
            for (int m = 1; m < 16; m <<= 1){
                ss.x += __shfl_xor(ss.x, m);
                ss.y += __shfl_xor(ss.y, m);
                ss.z += __shfl_xor(ss.z, m);
                ss.w += __shfl_xor(ss.w, m);
            }
            f32x4 inv;
            inv.x = 1.0f / sqrtf(ss.x * 0.03125f + 1e-6f);
            inv.y = 1.0f / sqrtf(ss.y * 0.03125f + 1e-6f);
            inv.z = 1.0f / sqrtf(ss.z * 0.03125f + 1e-6f);
            inv.w = 1.0f / sqrtf(ss.w * 0.03125f + 1e-6f);
            acc[mi][2 * g]     = a0 * inv;
            acc[mi][2 * g + 1] = a1 * inv;
        }
    }

    if constexpr (EPI == 0){
        const int zsel = col0 >> 12;          // 0:Q 1:K 2:V
        const int cbm  = (col0 & 4095) + wn * 64 + (lane & 15);
        if (zsel == 0){
            const float sg0 = blade_sign(lane & 15, lane & 15);
            const float sg1 = blade_sign(16 | (lane & 15), 16 | (lane & 15));
            #pragma unroll
            for (int mi = 0; mi < 8; ++mi)
                #pragma unroll
                for (int ni = 0; ni < 4; ++ni){
                    const f32x4 v = acc[mi][ni] * ((ni & 1) ? sg1 : sg0);
                    #pragma unroll
                    for (int j = 0; j < 4; ++j)
                        OQ[(size_t)(rb + mi * 16 + j) * 4096 + (cbm + ni * 16)] = f2h(v[j]);
                }
        } else if (zsel == 1){
            #pragma unroll
            for (int mi = 0; mi < 8; ++mi)
                #pragma unroll
                for (int ni = 0; ni < 4; ++ni)
                    #pragma unroll
                    for (int j = 0; j < 4; ++j)
                        OK[(size_t)(rb + mi * 16 + j) * 4096 + (cbm + ni * 16)] = f2h(acc[mi][ni][j]);
        } else {
            // V^T store: (b,h,f,t), 4 consecutive t per lane
            #pragma unroll
            for (int mi = 0; mi < 8; ++mi){
                const int r = rb + mi * 16;
                const int b = r >> 10, tt = r & 1023;
                #pragma unroll
                for (int ni = 0; ni < 4; ++ni){
                    const int c = cbm + ni * 16;
                    const int h = c >> 9, f = c & 511;
                    s16x4 pv;
                    #pragma unroll
                    for (int j = 0; j < 4; ++j) pv[j] = f2h(acc[mi][ni][j]);
                    *reinterpret_cast<s16x4*>(OV + ((size_t)((b * 8 + h) * 512 + f)) * 1024 + tt) = pv;
                }
            }
        }
    }
    if constexpr (EPI == 3){
        const int cb = col0 + wn * 64 + (lane & 15);
        #pragma unroll
        for (int mi = 0; mi < 8; ++mi)
            #pragma unroll
            for (int ni = 0; ni < 4; ++ni)
                #pragma unroll
                for (int j = 0; j < 4; ++j)
                    OutF[(size_t)(rb + mi * 16 + j) * 4096 + (cb + ni * 16)] = acc[mi][ni][j];
    }
}

// =======================================================================
// 128x128 ring-3 pipelined GEMM (proven R6-R10): BK=32, 4 waves, 48 KB LDS
// -> 3 blocks/CU. vmcnt(4) counted, peeled tail. XOR swizzle. setprio.
// Used for PV (EPI=5, batched over z).
// =======================================================================
#define R3_TILE(T, WN, PF)                                                      \
  {                                                                             \
    const int bb = cur * 8192;                                                  \
    wait_vm(WN);                                                                \
    __builtin_amdgcn_s_barrier();                                               \
    asm volatile("" ::: "memory");                                              \
    __builtin_amdgcn_sched_barrier(0);                                          \
    const int sb = stg * 8192;                                                  \
    if (PF){                                                                    \
        GLOAD_LDS(gA0 + (size_t)((T) + 2) * 32, lds + sb + dA0);                \
        GLOAD_LDS(gA1 + (size_t)((T) + 2) * 32, lds + sb + dA1);                \
    }                                                                           \
    f16x8 av[4], bv[4];                                                         \
    _Pragma("unroll")                                                           \
    for (int i = 0; i < 4; ++i)                                                 \
        av[i] = *reinterpret_cast<const f16x8*>(lds + bb + ard + i * 512);      \
    bv[0] = *reinterpret_cast<const f16x8*>(lds + bb + brd + 0 * 512);          \
    bv[1] = *reinterpret_cast<const f16x8*>(lds + bb + brd + 1 * 512);          \
    __builtin_amdgcn_s_setprio(1);                                              \
    _Pragma("unroll")                                                           \
    for (int mi = 0; mi < 4; ++mi)                                              \
        _Pragma("unroll")                                                       \
        for (int ni = 0; ni < 2; ++ni)                                          \
            acc[mi][ni] = __builtin_amdgcn_mfma_f32_16x16x32_f16(               \
                av[mi], bv[ni], acc[mi][ni], 0, 0, 0);                          \
    __builtin_amdgcn_s_setprio(0);                                              \
    if (PF){                                                                    \
        GLOAD_LDS(gB0 + (size_t)((T) + 2) * 32, lds + sb + dB0);                \
        GLOAD_LDS(gB1 + (size_t)((T) + 2) * 32, lds + sb + dB1);                \
    }                                                                           \
    bv[2] = *reinterpret_cast<const f16x8*>(lds + bb + brd + 2 * 512);          \
    bv[3] = *reinterpret_cast<const f16x8*>(lds + bb + brd + 3 * 512);          \
    __builtin_amdgcn_s_setprio(1);                                              \
    _Pragma("unroll")                                                           \
    for (int mi = 0; mi < 4; ++mi)                                              \
        _Pragma("unroll")                                                       \
        for (int ni = 2; ni < 4; ++ni)                                          \
            acc[mi][ni] = __builtin_amdgcn_mfma_f32_16x16x32_f16(               \
                av[mi], bv[ni], acc[mi][ni], 0, 0, 0);                          \
    __builtin_amdgcn_s_setprio(0);                                              \
    cur = (cur == 2) ? 0 : cur + 1;                                             \
    stg = (stg == 2) ? 0 : stg + 1;                                             \
  }

__global__ __launch_bounds__(256, 3) void versor_gemm_pv(
    const short* __restrict__ Abase, int lda,
    const short* __restrict__ Bbase, int ldb,
    int K, short* __restrict__ OutP)
{
    __shared__ short lds[3 * 8192];

    const int tid  = threadIdx.x;
    const int lane = tid & 63;
    const int wid  = tid >> 6;
    const int wr   = wid >> 1;
    const int wc   = wid & 1;
    const int z    = blockIdx.z;

    const short* A = Abase + (size_t)z * 1024 * 2048;
    const short* B = Bbase + (size_t)z * 512 * 1024;
    const int row0 = blockIdx.y * 128;
    const int col0 = blockIdx.x * 128;

    const int jsw = ((lane & 3) ^ ((lane >> 3) & 3)) * 8;
    const short* gA0 = A + (size_t)(row0 + wid * 16 + (lane >> 2)) * lda + jsw;
    const short* gA1 = gA0 + (size_t)64 * lda;
    const short* gB0 = B + (size_t)(col0 + wid * 16 + (lane >> 2)) * ldb + jsw;
    const short* gB1 = gB0 + (size_t)64 * ldb;
    const int dA0 = wid * 512,        dA1 = 2048 + wid * 512;
    const int dB0 = 4096 + wid * 512, dB1 = 6144 + wid * 512;

    const int swz = ((lane >> 4) ^ (((lane & 15) >> 1) & 3)) * 8;
    const int ard = (wr * 64 + (lane & 15)) * 32 + swz;
    const int brd = 4096 + (wc * 64 + (lane & 15)) * 32 + swz;

    f32x4 acc[4][4];
    #pragma unroll
    for (int i = 0; i < 4; ++i)
        #pragma unroll
        for (int j = 0; j < 4; ++j)
            acc[i][j] = (f32x4){0.f, 0.f, 0.f, 0.f};

    const int NT = K >> 5;

    #pragma unroll
    for (int pt = 0; pt < 2; ++pt){
        const int sb = pt * 8192;
        GLOAD_LDS(gA0 + pt * 32, lds + sb + dA0);
        GLOAD_LDS(gA1 + pt * 32, lds + sb + dA1);
        GLOAD_LDS(gB0 + pt * 32, lds + sb + dB0);
        GLOAD_LDS(gB1 + pt * 32, lds + sb + dB1);
    }

    int cur = 0, stg = 2;
    for (int t = 0; t < NT - 1; ++t)
        R3_TILE(t, 4, (t + 2 < NT))
    R3_TILE(NT - 1, 0, false)

    const int rb = row0 + wr * 64 + (lane >> 4) * 4;
    const int cb = col0 + wc * 64 + (lane & 15);
    const int b = z >> 3, h = z & 7;
    #pragma unroll
    for (int mi = 0; mi < 4; ++mi)
        #pragma unroll
        for (int ni = 0; ni < 4; ++ni)
            #pragma unroll
            for (int j = 0; j < 4; ++j)
                OutP[(size_t)(b * 1024 + rb + mi * 16 + j) * 4096 + h * 512 + (cb + ni * 16)]
                    = f2h(acc[mi][ni][j]);
}

// =======================================================================
// Scores kernel (256x256, 8 waves, ring-4, dyn 128KB LDS) with torque
// epilogue. Peeled tail (vmcnt 8 -> 4 -> 0).
// =======================================================================
#define SC_TILE(T, WN, PF)                                                      \
  {                                                                             \
    const int bb = ((T) & 3) * 16384;                                           \
    wait_vm(WN);                                                                \
    __builtin_amdgcn_s_barrier();                                               \
    asm volatile("" ::: "memory");                                              \
    __builtin_amdgcn_sched_barrier(0);                                          \
    if (PF){                                                                    \
        const int nb = (((T) + 3) & 3) * 16384;                                 \
        GLOAD_LDS(gA0 + (size_t)((T) + 3) * 32, lds + nb + dA0);                \
        GLOAD_LDS(gA1 + (size_t)((T) + 3) * 32, lds + nb + dA1);                \
    }                                                                           \
    f16x8 av[4], bv[4];                                                         \
    _Pragma("unroll")                                                           \
    for (int i = 0; i < 4; ++i){                                                \
        av[i] = *reinterpret_cast<const f16x8*>(lds + bb + ard + i * 512);      \
        bv[i] = *reinterpret_cast<const f16x8*>(lds + bb + brd + i * 512);      \
    }                                                                           \
    __builtin_amdgcn_s_setprio(1);                                              \
    _Pragma("unroll")                                                           \
    for (int mi = 0; mi < 4; ++mi)                                              \
        _Pragma("unroll")                                                       \
        for (int ni = 0; ni < 4; ++ni)                                          \
            acc[mi][ni] = __builtin_amdgcn_mfma_f32_16x16x32_f16(               \
                av[mi], bv[ni], acc[mi][ni], 0, 0, 0);                          \
    __builtin_amdgcn_s_setprio(0);                                              \
    if (PF){                                                                    \
        const int nb = (((T) + 3) & 3) * 16384;                                 \
        GLOAD_LDS(gB0 + (size_t)((T) + 3) * 32, lds + nb + dB0);                \
        GLOAD_LDS(gB1 + (size_t)((T) + 3) * 32, lds + nb + dB1);                \
    }                                                                           \
    f16x8 aw[4];                                                                \
    _Pragma("unroll")                                                           \
    for (int i = 0; i < 4; ++i)                                                 \
        aw[i] = *reinterpret_cast<const f16x8*>(lds + bb + ard + (4 + i) * 512);\
    __builtin_amdgcn_s_setprio(1);                                              \
    _Pragma("unroll")                                                           \
    for (int mi = 0; mi < 4; ++mi)                                              \
        _Pragma("unroll")                                                       \
        for (int ni = 0; ni < 4; ++ni)                                          \
            acc[4 + mi][ni] = __builtin_amdgcn_mfma_f32_16x16x32_f16(           \
                aw[mi], bv[ni], acc[4 + mi][ni], 0, 0, 0);                      \
    __builtin_amdgcn_s_setprio(0);                                              \
  }

__global__ __launch_bounds__(512, 2) void versor_gemm_sc(
    const short* __restrict__ Qbase, const short* __restrict__ Kbase,
    int K, float* __restrict__ OutP,
    const float* __restrict__ NqP, const float* __restrict__ NkP,
    const float* __restrict__ LamP)
{
    extern __shared__ short lds[];

    const int tid  = threadIdx.x;
    const int lane = tid & 63;
    const int wid  = tid >> 6;
    const int wm   = wid >> 2;
    const int wn   = wid & 3;
    const int z    = blockIdx.z;

    const int b = z >> 3, h = z & 7;
    const size_t off = (size_t)b * 1024 * 4096 + (size_t)h * 512;
    const short* A = Qbase + off;
    const short* B = Kbase + off;
    const int lda = 4096, ldb = 4096;
    const int row0 = blockIdx.y * 256;
    const int col0 = blockIdx.x * 256;

    const int jsw = ((lane & 3) ^ ((lane >> 3) & 3)) * 8;
    const short* gA0 = A + (size_t)(row0 + wid * 32 + (lane >> 2)) * lda + jsw;
    const short* gA1 = gA0 + (size_t)16 * lda;
    const short* gB0 = B + (size_t)(col0 + wid * 32 + (lane >> 2)) * ldb + jsw;
    const short* gB1 = gB0 + (size_t)16 * ldb;
    const int dA0 = wid * 1024, dA1 = dA0 + 512;
    const int dB0 = 8192 + wid * 1024, dB1 = dB0 + 512;

    const int swz = ((lane >> 4) ^ (((lane & 15) >> 1) & 3)) * 8;
    const int ard = (wm * 128 + (lane & 15)) * 32 + swz;
    const int brd = 8192 + (wn * 64 + (lane & 15)) * 32 + swz;

    f32x4 acc[8][4];
    #pragma unroll
    for (int i = 0; i < 8; ++i)
        #pragma unroll
        for (int j = 0; j < 4; ++j)
            acc[i][j] = (f32x4){0.f, 0.f, 0.f, 0.f};

    const int NT = K >> 5;   // 16

    #pragma unroll
    for (int pt = 0; pt < 3; ++pt){
        const int bb = pt * 16384;
        GLOAD_LDS(gA0 + pt * 32, lds + bb + dA0);
        GLOAD_LDS(gA1 + pt * 32, lds + bb + dA1);
        GLOAD_LDS(gB0 + pt * 32, lds + bb + dB0);
        GLOAD_LDS(gB1 + pt * 32, lds + bb + dB1);
    }

    for (int t = 0; t < NT - 2; ++t)
        SC_TILE(t, 8, (t + 3 < NT))
    SC_TILE(NT - 2, 4, false)
    SC_TILE(NT - 1, 0, false)

    const int rb = row0 + wm * 128 + (lane >> 4) * 4;
    const int cb = col0 + wn * 64 + (lane & 15);

    float* Of = OutP + (size_t)z * 1024 * 1024;
    const float lam = *LamP;
    const float* nq = NqP + z * 1024;
    const float* nk = NkP + z * 1024;
    #pragma unroll
    for (int mi = 0; mi < 8; ++mi)
        #pragma unroll
        for (int j = 0; j < 4; ++j){
            const int r = rb + mi * 16 + j;
            const float qn = nq[r];
            #pragma unroll
            for (int ni = 0; ni < 4; ++ni){
                const int c = cb + ni * 16;
                const float sc = acc[mi][ni][j];
                const float tq = sqrtf(fmaxf(qn * nk[c] - sc * sc, 0.0f) + 1e-6f);
                Of[(size_t)r * 1024 + c] = 0.25f * (sc + lam * tq);
            }
        }
}

// =======================================================================
extern "C" void kernel_launch(void* const* d_in, const int* in_sizes, int n_in,
                              void* d_out, int out_size, void* d_ws, size_t ws_size,
                              hipStream_t stream)
{
    (void)in_sizes; (void)n_in; (void)out_size; (void)ws_size;
    const float* x   = (const float*)d_in[0];
    const float* Wq  = (const float*)d_in[1];
    const float* Wk  = (const float*)d_in[2];
    const float* Wv  = (const float*)d_in[3];
    const float* Wo  = (const float*)d_in[4];
    const float* lam = (const float*)d_in[5];
    float* out = (float*)d_out;
    char*  ws  = (char*)d_ws;

    // workspace layout (~160.2 MB peak)
    short* Xf   = (short*)(ws);                             // 16 MB; later attn-out
    short* WmT3 = (short*)(ws + (16u  << 20));              // 96 MB (q,k,v); dead after QKV
    short* Qf   = (short*)(ws + (112u << 20));              // 16 MB
    short* Kf   = (short*)(ws + (128u << 20));              // 16 MB
    short* Vt   = (short*)(ws + (144u << 20));              // 16 MB (B,H,512,1024) f16
    float* Nq   = (float*)(ws + (160u << 20));              // 64 KB
    float* Nk   = (float*)(ws + (160u << 20) + (64u << 10));// 64 KB
    float* Sc   = (float*)(ws + (16u  << 20));              // 64 MB, overlays WmT3[0:64MB]
    short* WmTo = (short*)(ws + (80u  << 20));              // 32 MB, overlays WmT3[64:96MB]
    short* Attn = Xf;                                       // 16 MB, overlays Xf

    const int SC_LDS = 131072;
    const int W_LDS  = 73728;
    hipFuncSetAttribute(reinterpret_cast<const void*>(versor_gemm_sc),
                        hipFuncAttributeMaxDynamicSharedMemorySize, SC_LDS);
    hipFuncSetAttribute(reinterpret_cast<const void*>(versor_gemm_wide<0, 12>),
                        hipFuncAttributeMaxDynamicSharedMemorySize, W_LDS);
    hipFuncSetAttribute(reinterpret_cast<const void*>(versor_gemm_wide<3, 4>),
                        hipFuncAttributeMaxDynamicSharedMemorySize, W_LDS);

    dim3 blk(256), blk8(512);
    cast_f32_f16<<<4096, blk, 0, stream>>>(x, Xf);

    dim3 gw3(8192, 3);
    build_wmat3<<<gw3, blk, 0, stream>>>(Wq, Wk, Wv, WmT3);

    // fused QKV (R8's proven qkv2): 256x128 tiles, grid (96, 8) = 768 blocks
    dim3 gqkv(96, 8, 1);
    versor_gemm_wide<0, 12><<<gqkv, blk, W_LDS, stream>>>(
        Xf, WmT3, Qf, Kf, Vt, nullptr);

    row_norms<<<4096, blk, 0, stream>>>(Qf, Kf, Nq, Nk);

    build_wmat<<<8192, blk, 0, stream>>>(Wo, WmTo);

    dim3 gsc(4, 4, 16);      // 256 blocks, 1/CU
    versor_gemm_sc<<<gsc, blk8, SC_LDS, stream>>>(Qf, Kf, 512, Sc, Nq, Nk, lam);
    softmax_rows<<<4096, blk, 0, stream>>>(Sc);

    dim3 gpv(4, 8, 16);      // 512 blocks
    versor_gemm_pv<<<gpv, blk, 0, stream>>>(
        (const short*)Sc, 2048, Vt, 1024, 1024, Attn);

    // final projection on the same wide structure: grid (32, 8) = 256 blocks,
    // all co-resident at 2/CU; XCD swizzle CPX=4
    dim3 gfin(32, 8, 1);
    versor_gemm_wide<3, 4><<<gfin, blk, W_LDS, stream>>>(
        Attn, WmTo, nullptr, nullptr, nullptr, out);
}